// Round 1
// baseline (12019.127 us; speedup 1.0000x reference)
//
#include <hip/hip_runtime.h>
#include <hip/hip_bf16.h>
#include <math.h>

// Problem constants
#define Bn 64
#define Tn 512
#define In 256
#define Hn 1024
#define Fn 11
#define TP1 513       // T+1 slots in r history (slot 0 = h0)
#define NKB 40        // K=1280 / 32

typedef __attribute__((ext_vector_type(8))) short short8;  // 8 bf16 (4 VGPRs)
typedef __attribute__((ext_vector_type(4))) float f32x4;
typedef unsigned short u16;
typedef unsigned int u32;
typedef __hip_bfloat16 bf16;

__device__ __forceinline__ float sigm(float x) { return 1.0f / (1.0f + expf(-x)); }
__device__ __forceinline__ short8 ld8(const bf16* p) { return *(const short8*)p; }

// ---------------- cast inputs to bf16, zero barrier counters ----------------
__global__ void k_cast(const float* __restrict__ x, const float* __restrict__ whh,
                       const float* __restrict__ wih, const float* __restrict__ h0,
                       bf16* __restrict__ xb, bf16* __restrict__ whhb,
                       bf16* __restrict__ wihb, bf16* __restrict__ rb,
                       u32* __restrict__ bar)
{
  long i = (long)blockIdx.x * 256 + threadIdx.x;
  if (i < 8388608L) {                                   // x: B*T*I
    xb[i] = __float2bfloat16(x[i]);
  } else if (i < 8388608L + 4194304L) {                 // W_hh: 4H*H
    long j = i - 8388608L; whhb[j] = __float2bfloat16(whh[j]);
  } else if (i < 8388608L + 4194304L + 1048576L) {      // W_ih: 4H*I
    long j = i - 8388608L - 4194304L; wihb[j] = __float2bfloat16(wih[j]);
  } else if (i < 8388608L + 4194304L + 1048576L + 65536L) {  // h0 -> r slot 0
    long j = i - 8388608L - 4194304L - 1048576L;
    int b = (int)(j >> 10), h = (int)(j & 1023);
    rb[((long)b * TP1) * Hn + h] = __float2bfloat16(h0[j]);
  }
  if (blockIdx.x == 0 && threadIdx.x < 128) bar[threadIdx.x] = 0u;
}

// ---------------- fold post-LSTM linears: G[16][H] = V @ W_sh ----------------
// rows 0..10: W_state, 11: W_reward, 12: w_att_s, 13: w_att_r, 14/15: zero
__global__ void k_fold_part(const float* __restrict__ Wsh, const float* __restrict__ Wst,
                            const float* __restrict__ Wrw, const float* __restrict__ was,
                            const float* __restrict__ war, float* __restrict__ Gpart)
{
  int k = blockIdx.x * 256 + threadIdx.x;   // grid.x = 4 -> k in [0,1024)
  int j = blockIdx.y;                       // 16
  int h0 = blockIdx.z * 128;                // grid.z = 8
  const float* V = nullptr;
  if (j < 11) V = Wst + j * Hn;
  else if (j == 11) V = Wrw;
  else if (j == 12) V = was;
  else if (j == 13) V = war;
  float acc = 0.f;
  if (V) {
    for (int h = h0; h < h0 + 128; ++h) acc += V[h] * Wsh[(long)h * Hn + k];
  }
  Gpart[((long)blockIdx.z * 16 + j) * Hn + k] = acc;
}

__global__ void k_g2b(const float* __restrict__ Gpart, bf16* __restrict__ Gb)
{
  int i = blockIdx.x * 256 + threadIdx.x;   // 16384
  float s = 0.f;
  for (int z = 0; z < 8; ++z) s += Gpart[(long)z * 16384 + i];
  Gb[i] = __float2bfloat16(s);
}

// constants folded through the attention average (weights sum to 1)
__global__ void k_const(const float* __restrict__ bsh, const float* __restrict__ Wst,
                        const float* __restrict__ bst, const float* __restrict__ Wrw,
                        const float* __restrict__ brw, const float* __restrict__ was,
                        const float* __restrict__ bas, const float* __restrict__ war,
                        const float* __restrict__ bar_, float* __restrict__ cv)
{
  int j = threadIdx.x;
  if (j >= 16) return;
  const float* V = nullptr; float bb = 0.f;
  if (j < 11) { V = Wst + j * Hn; bb = bst[j]; }
  else if (j == 11) { V = Wrw; bb = brw[0]; }
  else if (j == 12) { V = was; bb = bas[0]; }
  else if (j == 13) { V = war; bb = bar_[0]; }
  float acc = 0.f;
  if (V) for (int h = 0; h < Hn; ++h) acc += bsh[h] * V[h];
  cv[j] = acc + bb;
}

// ---------------- the sequential LSTM, persistent cooperative kernel ----------------
// 4 independent batch-groups (16 batches each) x 64 WGs. WG owns 16 h-dims.
// Wave (4/WG) owns 4 h-dims -> 16 rows of [W_hh|W_ih], held in VGPRs as MFMA B-frags.
__global__ void __launch_bounds__(256, 1)
k_lstm(const bf16* __restrict__ xb, const bf16* __restrict__ whhb,
       const bf16* __restrict__ wihb, const float* __restrict__ bih,
       const float* __restrict__ bhh, const float* __restrict__ c0,
       bf16* __restrict__ rb, float* __restrict__ outH, float* __restrict__ outC,
       u32* bar)
{
  const int tid = threadIdx.x;
  const int w = tid >> 6, l = tid & 63;
  const int g = blockIdx.x >> 6;       // batch group 0..3
  const int mem = blockIdx.x & 63;     // member in group
  const int lo16 = l & 15, q = l >> 4;
  const int dbase = (mem << 4) + (w << 2);   // first of this wave's 4 h-dims
  const int gate = lo16 >> 2, dd = lo16 & 3; // this lane's B-frag row: gate, dim-offset
  const long grow = (long)gate * Hn + dbase + dd;
  const int koff = q * 8;

  // W B-fragments resident in VGPRs for the whole kernel
  short8 wf[NKB];
  {
    const bf16* whp = whhb + grow * Hn + koff;
    const bf16* wip = wihb + grow * In + koff;
#pragma unroll
    for (int kb = 0; kb < 32; ++kb) wf[kb] = ld8(whp + kb * 32);
#pragma unroll
    for (int kb = 32; kb < NKB; ++kb) wf[kb] = ld8(wip + (kb - 32) * 32);
  }

  // gate-phase lane mapping: lane -> (batch-local, dim-local)
  const int bl = l >> 2, d_ = l & 3;
  const int bb = (g << 4) + bl;          // global batch
  const int dloc = dbase + d_;           // global h-dim
  const float bi0 = bih[0 * Hn + dloc] + bhh[0 * Hn + dloc];
  const float bi1 = bih[1 * Hn + dloc] + bhh[1 * Hn + dloc];
  const float bi2 = bih[2 * Hn + dloc] + bhh[2 * Hn + dloc];
  const float bi3 = bih[3 * Hn + dloc] + bhh[3 * Hn + dloc];
  float cst = c0[(long)bb * Hn + dloc];  // fp32 cell state, register-resident

  // A-operand base pointers (M-tile = the group's 16 batches)
  const int bA = (g << 4) + lo16;
  const bf16* rA = rb + ((long)bA * TP1) * Hn + koff;
  const bf16* xA = xb + ((long)bA * Tn) * In + koff;
  bf16* rW = rb + ((long)bb * TP1 + 1) * Hn + dloc;

  u32* mybar = bar + g * 32;             // 128B-spaced counters per group
  __shared__ float zbuf[4][16][17];

  for (int t = 0; t < Tn; ++t) {
    const bf16* rp = rA + (long)t * Hn;
    const bf16* xp = xA + (long)t * In;
    f32x4 a0 = {0,0,0,0}, a1 = {0,0,0,0}, a2 = {0,0,0,0}, a3 = {0,0,0,0};
#pragma unroll
    for (int kb = 0; kb < 32; kb += 4) {
      a0 = __builtin_amdgcn_mfma_f32_16x16x32_bf16(ld8(rp + kb * 32),       wf[kb],     a0, 0, 0, 0);
      a1 = __builtin_amdgcn_mfma_f32_16x16x32_bf16(ld8(rp + kb * 32 + 32),  wf[kb + 1], a1, 0, 0, 0);
      a2 = __builtin_amdgcn_mfma_f32_16x16x32_bf16(ld8(rp + kb * 32 + 64),  wf[kb + 2], a2, 0, 0, 0);
      a3 = __builtin_amdgcn_mfma_f32_16x16x32_bf16(ld8(rp + kb * 32 + 96),  wf[kb + 3], a3, 0, 0, 0);
    }
#pragma unroll
    for (int kb = 32; kb < NKB; kb += 4) {
      a0 = __builtin_amdgcn_mfma_f32_16x16x32_bf16(ld8(xp + (kb - 32) * 32),      wf[kb],     a0, 0, 0, 0);
      a1 = __builtin_amdgcn_mfma_f32_16x16x32_bf16(ld8(xp + (kb - 32) * 32 + 32), wf[kb + 1], a1, 0, 0, 0);
      a2 = __builtin_amdgcn_mfma_f32_16x16x32_bf16(ld8(xp + (kb - 32) * 32 + 64), wf[kb + 2], a2, 0, 0, 0);
      a3 = __builtin_amdgcn_mfma_f32_16x16x32_bf16(ld8(xp + (kb - 32) * 32 + 96), wf[kb + 3], a3, 0, 0, 0);
    }
    f32x4 z = (a0 + a1) + (a2 + a3);
    // C/D layout: z[m = q*4+r][n = lo16]
#pragma unroll
    for (int r = 0; r < 4; ++r) zbuf[w][q * 4 + r][lo16] = z[r];
    __syncthreads();

    float zi = zbuf[w][bl][0 + d_]  + bi0;
    float zf = zbuf[w][bl][4 + d_]  + bi1;
    float zg = zbuf[w][bl][8 + d_]  + bi2;
    float zo = zbuf[w][bl][12 + d_] + bi3;
    float iv = sigm(zi), fv = sigm(zf), gv = tanhf(zg), ov = sigm(zo);
    cst = fv * cst + iv * gv;
    float hv = ov * tanhf(cst);
    rW[(long)t * Hn] = __float2bfloat16(hv);
    if (t == Tn - 1) {
      outH[(long)bb * Hn + dloc] = hv;
      outC[(long)bb * Hn + dloc] = cst;
    }

    // group barrier: cumulative count, agent-scope release/acquire
    __syncthreads();                     // drains vmcnt(0) -> h stores in L2
    if (tid == 0) {
      __threadfence();                   // L2 writeback (cross-XCD release)
      __hip_atomic_fetch_add(mybar, 1u, __ATOMIC_RELEASE, __HIP_MEMORY_SCOPE_AGENT);
      const u32 target = 64u * (u32)(t + 1);
      while (__hip_atomic_load(mybar, __ATOMIC_ACQUIRE, __HIP_MEMORY_SCOPE_AGENT) < target) {
        __builtin_amdgcn_s_sleep(2);
      }
      __threadfence();                   // invalidate L1/L2 (acquire)
    }
    __syncthreads();
  }
}

// ---------------- project r onto folded 16-dim basis: P[B*T][16] ----------------
__global__ void k_proj(const bf16* __restrict__ rb, const bf16* __restrict__ Gb,
                       const float* __restrict__ cv, float* __restrict__ P)
{
  const int tid = threadIdx.x;
  const int w = tid >> 6, l = tid & 63;
  const int lo16 = l & 15, q = l >> 4;
  const int row = blockIdx.x * 64 + w * 16 + lo16;    // (b,t) flat
  const int b = row >> 9, t = row & 511;
  const bf16* ap = rb + ((long)b * TP1 + t + 1) * Hn + q * 8;
  const bf16* gp = Gb + (long)lo16 * Hn + q * 8;
  f32x4 a0 = {0,0,0,0}, a1 = {0,0,0,0};
#pragma unroll
  for (int kb = 0; kb < 32; kb += 2) {
    a0 = __builtin_amdgcn_mfma_f32_16x16x32_bf16(ld8(ap + kb * 32),      ld8(gp + kb * 32),      a0, 0, 0, 0);
    a1 = __builtin_amdgcn_mfma_f32_16x16x32_bf16(ld8(ap + kb * 32 + 32), ld8(gp + kb * 32 + 32), a1, 0, 0, 0);
  }
  f32x4 z = a0 + a1;
  float c = cv[lo16];
  const int rowbase = blockIdx.x * 64 + w * 16;
#pragma unroll
  for (int r = 0; r < 4; ++r)
    P[(long)(rowbase + q * 4 + r) * 16 + lo16] = z[r] + c;
}

// ---------------- per-batch online-softmax prefix scan ----------------
__global__ void k_scan(const float* __restrict__ P, float* __restrict__ outS,
                       float* __restrict__ outR)
{
  __shared__ float sp[Tn * 16];
  const int b = blockIdx.x, tid = threadIdx.x;
  for (int i = tid; i < Tn * 16; i += 64) sp[i] = P[(long)b * Tn * 16 + i];
  __syncthreads();
  const int j = tid;
  if (j < 12) {
    const bool isR = (j == 11);
    float m = -INFINITY, den = 0.f, num = 0.f;
    for (int t = 0; t < Tn; ++t) {
      float val = sp[t * 16 + j];
      float ll = sp[t * 16 + (isR ? 13 : 12)];
      float mn = fmaxf(m, ll);
      float al = __expf(m - mn);
      float e  = __expf(ll - mn);
      den = den * al + e;
      num = num * al + e * val;
      m = mn;
      float o = num / den;
      if (isR) outR[(long)b * Tn + t] = o;
      else     outS[(long)(b * Tn + t) * Fn + j] = o;
    }
  }
}

extern "C" void kernel_launch(void* const* d_in, const int* in_sizes, int n_in,
                              void* d_out, int out_size, void* d_ws, size_t ws_size,
                              hipStream_t stream)
{
  (void)in_sizes; (void)n_in; (void)out_size; (void)ws_size;
  const float* x    = (const float*)d_in[0];
  const float* h0   = (const float*)d_in[2];
  const float* c0   = (const float*)d_in[3];
  const float* Wih  = (const float*)d_in[4];
  const float* Whh  = (const float*)d_in[5];
  const float* bih  = (const float*)d_in[6];
  const float* bhh  = (const float*)d_in[7];
  const float* Wsh  = (const float*)d_in[8];
  const float* bsh  = (const float*)d_in[9];
  const float* was  = (const float*)d_in[10];
  const float* bas  = (const float*)d_in[11];
  const float* war  = (const float*)d_in[12];
  const float* barr = (const float*)d_in[13];
  const float* Wst  = (const float*)d_in[14];
  const float* bst  = (const float*)d_in[15];
  const float* Wrw  = (const float*)d_in[16];
  const float* brw  = (const float*)d_in[17];

  char* ws = (char*)d_ws;
  size_t off = 0;
  auto alloc = [&](size_t bytes) -> void* {
    void* p = ws + off; off += (bytes + 255) & ~(size_t)255; return p;
  };
  bf16* xb    = (bf16*)alloc((size_t)Bn * Tn * In * 2);
  bf16* whhb  = (bf16*)alloc((size_t)4 * Hn * Hn * 2);
  bf16* wihb  = (bf16*)alloc((size_t)4 * Hn * In * 2);
  bf16* rb    = (bf16*)alloc((size_t)Bn * TP1 * Hn * 2);
  bf16* Gb    = (bf16*)alloc((size_t)16 * Hn * 2);
  float* Gpart= (float*)alloc((size_t)8 * 16 * Hn * 4);
  float* cv   = (float*)alloc(16 * 4);
  float* P    = (float*)alloc((size_t)Bn * Tn * 16 * 4);
  u32*  barp  = (u32*)alloc(512);

  float* outS = (float*)d_out;
  float* outR = outS + (size_t)Bn * Tn * Fn;
  float* outH = outR + (size_t)Bn * Tn;
  float* outC = outH + (size_t)Bn * Hn;

  const long NCAST = 8388608L + 4194304L + 1048576L + 65536L;
  k_cast<<<dim3((unsigned)(NCAST / 256)), 256, 0, stream>>>(x, Whh, Wih, h0, xb, whhb, wihb, rb, barp);
  k_fold_part<<<dim3(4, 16, 8), 256, 0, stream>>>(Wsh, Wst, Wrw, was, war, Gpart);
  k_g2b<<<64, 256, 0, stream>>>(Gpart, Gb);
  k_const<<<1, 64, 0, stream>>>(bsh, Wst, bst, Wrw, brw, was, bas, war, barr, cv);

  {
    void* args[] = { (void*)&xb, (void*)&whhb, (void*)&wihb, (void*)&bih, (void*)&bhh,
                     (void*)&c0, (void*)&rb, (void*)&outH, (void*)&outC, (void*)&barp };
    hipError_t e = hipLaunchCooperativeKernel((const void*)k_lstm, dim3(256), dim3(256),
                                              args, 0, stream);
    if (e != hipSuccess) {
      // fallback: plain launch (barrier is hand-rolled; 256 blocks at 1/CU co-reside)
      k_lstm<<<256, 256, 0, stream>>>(xb, whhb, wihb, bih, bhh, c0, rb, outH, outC, barp);
    }
  }

  k_proj<<<512, 256, 0, stream>>>(rb, Gb, cv, P);
  k_scan<<<64, 64, 0, stream>>>(P, outS, outR);
}

// Round 2
// 3076.813 us; speedup vs baseline: 3.9064x; 3.9064x over previous
//
#include <hip/hip_runtime.h>
#include <hip/hip_bf16.h>
#include <math.h>

// Problem constants
#define Bn 64
#define Tn 512
#define In 256
#define Hn 1024
#define Fn 11
#define TP1 513       // T+1 slots in r history (slot 0 = h0)

typedef __attribute__((ext_vector_type(8))) short short8;  // 8 bf16 (4 VGPRs)
typedef __attribute__((ext_vector_type(4))) float f32x4;
typedef unsigned short u16;
typedef unsigned int u32;
typedef unsigned long long u64;
typedef __hip_bfloat16 bf16;

__device__ __forceinline__ float sigm(float x) { return 1.0f / (1.0f + __expf(-x)); }
__device__ __forceinline__ short8 ld8(const bf16* p) { return *(const short8*)p; }

// ---------------- cast inputs to bf16, zero barrier flags ----------------
__global__ void k_cast(const float* __restrict__ x, const float* __restrict__ whh,
                       const float* __restrict__ wih, const float* __restrict__ h0,
                       bf16* __restrict__ xb, bf16* __restrict__ whhb,
                       bf16* __restrict__ wihb, bf16* __restrict__ rb,
                       u32* __restrict__ bar)
{
  long i = (long)blockIdx.x * 256 + threadIdx.x;
  if (i < 8388608L) {                                   // x: B*T*I
    xb[i] = __float2bfloat16(x[i]);
  } else if (i < 8388608L + 4194304L) {                 // W_hh: 4H*H
    long j = i - 8388608L; whhb[j] = __float2bfloat16(whh[j]);
  } else if (i < 8388608L + 4194304L + 1048576L) {      // W_ih: 4H*I
    long j = i - 8388608L - 4194304L; wihb[j] = __float2bfloat16(wih[j]);
  } else if (i < 8388608L + 4194304L + 1048576L + 65536L) {  // h0 -> r slot 0
    long j = i - 8388608L - 4194304L - 1048576L;
    int b = (int)(j >> 10), h = (int)(j & 1023);
    rb[((long)b * TP1) * Hn + h] = __float2bfloat16(h0[j]);
  }
  if (blockIdx.x == 0 && threadIdx.x < 256) bar[threadIdx.x] = 0u;  // 4 groups x 64 flags
}

// ---------------- fold post-LSTM linears: G[16][H] = V @ W_sh ----------------
// rows 0..10: W_state, 11: W_reward, 12: w_att_s, 13: w_att_r, 14/15: zero
__global__ void k_fold_part(const float* __restrict__ Wsh, const float* __restrict__ Wst,
                            const float* __restrict__ Wrw, const float* __restrict__ was,
                            const float* __restrict__ war, float* __restrict__ Gpart)
{
  int k = blockIdx.x * 256 + threadIdx.x;   // grid.x = 4 -> k in [0,1024)
  int j = blockIdx.y;                       // 16
  int h0 = blockIdx.z * 128;                // grid.z = 8
  const float* V = nullptr;
  if (j < 11) V = Wst + j * Hn;
  else if (j == 11) V = Wrw;
  else if (j == 12) V = was;
  else if (j == 13) V = war;
  float acc = 0.f;
  if (V) {
    for (int h = h0; h < h0 + 128; ++h) acc += V[h] * Wsh[(long)h * Hn + k];
  }
  Gpart[((long)blockIdx.z * 16 + j) * Hn + k] = acc;
}

__global__ void k_g2b(const float* __restrict__ Gpart, bf16* __restrict__ Gb)
{
  int i = blockIdx.x * 256 + threadIdx.x;   // 16384
  float s = 0.f;
  for (int z = 0; z < 8; ++z) s += Gpart[(long)z * 16384 + i];
  Gb[i] = __float2bfloat16(s);
}

// constants folded through the attention average (weights sum to 1)
__global__ void k_const(const float* __restrict__ bsh, const float* __restrict__ Wst,
                        const float* __restrict__ bst, const float* __restrict__ Wrw,
                        const float* __restrict__ brw, const float* __restrict__ was,
                        const float* __restrict__ bas, const float* __restrict__ war,
                        const float* __restrict__ bar_, float* __restrict__ cv)
{
  int j = threadIdx.x;
  if (j >= 16) return;
  const float* V = nullptr; float bb = 0.f;
  if (j < 11) { V = Wst + j * Hn; bb = bst[j]; }
  else if (j == 11) { V = Wrw; bb = brw[0]; }
  else if (j == 12) { V = was; bb = bas[0]; }
  else if (j == 13) { V = war; bb = bar_[0]; }
  float acc = 0.f;
  if (V) for (int h = 0; h < Hn; ++h) acc += bsh[h] * V[h];
  cv[j] = acc + bb;
}

// ---------------- the sequential LSTM, persistent cooperative kernel ----------------
// 4 batch-groups x 64 WGs. WG owns 16 h-dims (64 z-rows). Waves split K 4-way
// (10 kb-blocks each); all cross-WG traffic is relaxed agent-scope (sc0 sc1,
// served at Infinity Cache) -> NO buffer_inv / buffer_wbl2 cache maintenance.
__global__ void __launch_bounds__(256, 1)
k_lstm(const bf16* __restrict__ xb, const bf16* __restrict__ whhb,
       const bf16* __restrict__ wihb, const float* __restrict__ bih,
       const float* __restrict__ bhh, const float* __restrict__ c0,
       bf16* __restrict__ rb, float* __restrict__ outH, float* __restrict__ outC,
       u32* flags)
{
  const int tid = threadIdx.x;
  const int w = tid >> 6, l = tid & 63;
  const int lo16 = l & 15, q = l >> 4;
  const int g = blockIdx.x >> 6;       // batch group 0..3 (16 batches each)
  const int mem = blockIdx.x & 63;     // member in group
  const int bG0 = g << 4;

  // B-fragments in registers: wave w covers kb in [w*10, w*10+10); n-tile j = gate j.
  // B row for (gate j, lane lo16) = j*H + mem*16 + lo16.
  short8 wf[4][10];
  {
    const int wrow = (mem << 4) + lo16;
#pragma unroll
    for (int j = 0; j < 4; ++j) {
#pragma unroll
      for (int kk = 0; kk < 10; ++kk) {
        const int kb = w * 10 + kk;
        if (kb < 32)
          wf[j][kk] = ld8(whhb + (long)(j * Hn + wrow) * Hn + kb * 32 + q * 8);
        else
          wf[j][kk] = ld8(wihb + (long)(j * Hn + wrow) * In + (kb - 32) * 32 + q * 8);
      }
    }
  }

  // gate-phase mapping: thread -> (batch bl, local dim diml)
  const int bl = tid & 15, diml = tid >> 4;
  const int bb = bG0 + bl;
  const int dloc = (mem << 4) + diml;
  const float bi0 = bih[dloc]          + bhh[dloc];
  const float bi1 = bih[Hn + dloc]     + bhh[Hn + dloc];
  const float bi2 = bih[2 * Hn + dloc] + bhh[2 * Hn + dloc];
  const float bi3 = bih[3 * Hn + dloc] + bhh[3 * Hn + dloc];
  float cst = c0[(long)bb * Hn + dloc];

  // staging mapping: 16 threads per batch row
  const int sb = tid >> 4, tl = tid & 15;

  // LDS: A-tile 16 rows x (1280 dims *2B + 16B pad) + partial-z buffer
  __shared__ __align__(16) unsigned char Atile[16 * 2576];
  __shared__ float zbuf[4][4][16][17];   // [K-quarter][gate][diml][batch+pad]

  u32* fl = flags + g * 64;

  const u64* xrow = (const u64*)(xb + (long)(bG0 + sb) * Tn * In);
  const u64* rrow = (const u64*)(rb + (long)(bG0 + sb) * TP1 * Hn);
  u64* ldsr = (u64*)(Atile + sb * 2576);
  u64* ldsx = (u64*)(Atile + sb * 2576 + 2048);

  for (int t = 0; t < Tn; ++t) {
    // x prefetch (normal cached loads; independent of the recurrence)
    u64 xv[4];
    {
      const u64* xp = xrow + (long)t * (In / 4);
#pragma unroll
      for (int jx = 0; jx < 4; ++jx) xv[jx] = xp[tl + 16 * jx];
    }

    // wait for step t-1's h: poll 64 flags, relaxed agent loads (no fences)
    if (t > 0) {
      const u32 tgt = (u32)t;
      while (true) {
        u32 f = __hip_atomic_load(&fl[l], __ATOMIC_RELAXED, __HIP_MEMORY_SCOPE_AGENT);
        if (__ballot((l != mem) && (f < tgt)) == 0ULL) break;
      }
      __asm__ __volatile__("" ::: "memory");
    }

    // r staging: sc0 sc1 loads straight from IF (bypass non-coherent L1/L2)
    u64 rv[16];
    {
      const u64* rp = rrow + (long)t * (Hn / 4);
#pragma unroll
      for (int j = 0; j < 16; ++j)
        rv[j] = __hip_atomic_load(rp + tl + 16 * j, __ATOMIC_RELAXED, __HIP_MEMORY_SCOPE_AGENT);
    }
#pragma unroll
    for (int jx = 0; jx < 4; ++jx) ldsx[tl + 16 * jx] = xv[jx];
#pragma unroll
    for (int j = 0; j < 16; ++j) ldsr[tl + 16 * j] = rv[j];
    __syncthreads();

    // MFMA: wave w's K-quarter, A-frag reused across 4 gate-tiles
    f32x4 a0 = {0,0,0,0}, a1 = {0,0,0,0}, a2 = {0,0,0,0}, a3 = {0,0,0,0};
#pragma unroll
    for (int kk = 0; kk < 10; ++kk) {
      const int kb = w * 10 + kk;
      short8 af = *(const short8*)(Atile + lo16 * 2576 + (kb * 32 + q * 8) * 2);
      a0 = __builtin_amdgcn_mfma_f32_16x16x32_bf16(af, wf[0][kk], a0, 0, 0, 0);
      a1 = __builtin_amdgcn_mfma_f32_16x16x32_bf16(af, wf[1][kk], a1, 0, 0, 0);
      a2 = __builtin_amdgcn_mfma_f32_16x16x32_bf16(af, wf[2][kk], a2, 0, 0, 0);
      a3 = __builtin_amdgcn_mfma_f32_16x16x32_bf16(af, wf[3][kk], a3, 0, 0, 0);
    }
    // D layout: m(batch) = q*4+reg, n(diml) = lo16
#pragma unroll
    for (int r = 0; r < 4; ++r) {
      zbuf[w][0][lo16][q * 4 + r] = a0[r];
      zbuf[w][1][lo16][q * 4 + r] = a1[r];
      zbuf[w][2][lo16][q * 4 + r] = a2[r];
      zbuf[w][3][lo16][q * 4 + r] = a3[r];
    }
    __syncthreads();

    // gates: sum the 4 K-partials
    float zi = zbuf[0][0][diml][bl] + zbuf[1][0][diml][bl] + zbuf[2][0][diml][bl] + zbuf[3][0][diml][bl] + bi0;
    float zf = zbuf[0][1][diml][bl] + zbuf[1][1][diml][bl] + zbuf[2][1][diml][bl] + zbuf[3][1][diml][bl] + bi1;
    float zg = zbuf[0][2][diml][bl] + zbuf[1][2][diml][bl] + zbuf[2][2][diml][bl] + zbuf[3][2][diml][bl] + bi2;
    float zo = zbuf[0][3][diml][bl] + zbuf[1][3][diml][bl] + zbuf[2][3][diml][bl] + zbuf[3][3][diml][bl] + bi3;
    float iv = sigm(zi), fv = sigm(zf), gv = tanhf(zg), ov = sigm(zo);
    cst = fv * cst + iv * gv;
    float hv = ov * tanhf(cst);

    // packed u32 h store, relaxed agent (sc0 sc1 -> IF, no L2 dirty lines)
    float ph = __shfl_xor(hv, 16, 64);          // partner has diml^1
    u16 mb = __builtin_bit_cast(u16, __float2bfloat16(hv));
    u16 pb = __builtin_bit_cast(u16, __float2bfloat16(ph));
    if ((diml & 1) == 0) {
      u32 pack = (u32)mb | ((u32)pb << 16);
      u32* dst = (u32*)(rb + ((long)bb * TP1 + t + 1) * Hn + dloc);
      __hip_atomic_store(dst, pack, __ATOMIC_RELAXED, __HIP_MEMORY_SCOPE_AGENT);
    }
    if (t == Tn - 1) {
      outH[(long)bb * Hn + dloc] = hv;
      outC[(long)bb * Hn + dloc] = cst;
    }

    // drain this wave's stores to their coherence point, then block barrier
    __asm__ __volatile__("s_waitcnt vmcnt(0)" ::: "memory");
    __syncthreads();
    if (tid == 0 && t < Tn - 1)
      __hip_atomic_store(&fl[mem], (u32)(t + 1), __ATOMIC_RELAXED, __HIP_MEMORY_SCOPE_AGENT);
  }
}

// ---------------- project r onto folded 16-dim basis: P[B*T][16] ----------------
__global__ void k_proj(const bf16* __restrict__ rb, const bf16* __restrict__ Gb,
                       const float* __restrict__ cv, float* __restrict__ P)
{
  const int tid = threadIdx.x;
  const int w = tid >> 6, l = tid & 63;
  const int lo16 = l & 15, q = l >> 4;
  const int row = blockIdx.x * 64 + w * 16 + lo16;    // (b,t) flat
  const int b = row >> 9, t = row & 511;
  const bf16* ap = rb + ((long)b * TP1 + t + 1) * Hn + q * 8;
  const bf16* gp = Gb + (long)lo16 * Hn + q * 8;
  f32x4 a0 = {0,0,0,0}, a1 = {0,0,0,0};
#pragma unroll
  for (int kb = 0; kb < 32; kb += 2) {
    a0 = __builtin_amdgcn_mfma_f32_16x16x32_bf16(ld8(ap + kb * 32),      ld8(gp + kb * 32),      a0, 0, 0, 0);
    a1 = __builtin_amdgcn_mfma_f32_16x16x32_bf16(ld8(ap + kb * 32 + 32), ld8(gp + kb * 32 + 32), a1, 0, 0, 0);
  }
  f32x4 z = a0 + a1;
  float c = cv[lo16];
  const int rowbase = blockIdx.x * 64 + w * 16;
#pragma unroll
  for (int r = 0; r < 4; ++r)
    P[(long)(rowbase + q * 4 + r) * 16 + lo16] = z[r] + c;
}

// ---------------- per-batch online-softmax prefix scan ----------------
__global__ void k_scan(const float* __restrict__ P, float* __restrict__ outS,
                       float* __restrict__ outR)
{
  __shared__ float sp[Tn * 16];
  const int b = blockIdx.x, tid = threadIdx.x;
  for (int i = tid; i < Tn * 16; i += 64) sp[i] = P[(long)b * Tn * 16 + i];
  __syncthreads();
  const int j = tid;
  if (j < 12) {
    const bool isR = (j == 11);
    float m = -INFINITY, den = 0.f, num = 0.f;
    for (int t = 0; t < Tn; ++t) {
      float val = sp[t * 16 + j];
      float ll = sp[t * 16 + (isR ? 13 : 12)];
      float mn = fmaxf(m, ll);
      float al = __expf(m - mn);
      float e  = __expf(ll - mn);
      den = den * al + e;
      num = num * al + e * val;
      m = mn;
      float o = num / den;
      if (isR) outR[(long)b * Tn + t] = o;
      else     outS[(long)(b * Tn + t) * Fn + j] = o;
    }
  }
}

extern "C" void kernel_launch(void* const* d_in, const int* in_sizes, int n_in,
                              void* d_out, int out_size, void* d_ws, size_t ws_size,
                              hipStream_t stream)
{
  (void)in_sizes; (void)n_in; (void)out_size; (void)ws_size;
  const float* x    = (const float*)d_in[0];
  const float* h0   = (const float*)d_in[2];
  const float* c0   = (const float*)d_in[3];
  const float* Wih  = (const float*)d_in[4];
  const float* Whh  = (const float*)d_in[5];
  const float* bih  = (const float*)d_in[6];
  const float* bhh  = (const float*)d_in[7];
  const float* Wsh  = (const float*)d_in[8];
  const float* bsh  = (const float*)d_in[9];
  const float* was  = (const float*)d_in[10];
  const float* bas  = (const float*)d_in[11];
  const float* war  = (const float*)d_in[12];
  const float* barr = (const float*)d_in[13];
  const float* Wst  = (const float*)d_in[14];
  const float* bst  = (const float*)d_in[15];
  const float* Wrw  = (const float*)d_in[16];
  const float* brw  = (const float*)d_in[17];

  char* ws = (char*)d_ws;
  size_t off = 0;
  auto alloc = [&](size_t bytes) -> void* {
    void* p = ws + off; off += (bytes + 255) & ~(size_t)255; return p;
  };
  bf16* xb    = (bf16*)alloc((size_t)Bn * Tn * In * 2);
  bf16* whhb  = (bf16*)alloc((size_t)4 * Hn * Hn * 2);
  bf16* wihb  = (bf16*)alloc((size_t)4 * Hn * In * 2);
  bf16* rb    = (bf16*)alloc((size_t)Bn * TP1 * Hn * 2);
  bf16* Gb    = (bf16*)alloc((size_t)16 * Hn * 2);
  float* Gpart= (float*)alloc((size_t)8 * 16 * Hn * 4);
  float* cv   = (float*)alloc(16 * 4);
  float* P    = (float*)alloc((size_t)Bn * Tn * 16 * 4);
  u32*  barp  = (u32*)alloc(1024);

  float* outS = (float*)d_out;
  float* outR = outS + (size_t)Bn * Tn * Fn;
  float* outH = outR + (size_t)Bn * Tn;
  float* outC = outH + (size_t)Bn * Hn;

  const long NCAST = 8388608L + 4194304L + 1048576L + 65536L;
  k_cast<<<dim3((unsigned)(NCAST / 256)), 256, 0, stream>>>(x, Whh, Wih, h0, xb, whhb, wihb, rb, barp);
  k_fold_part<<<dim3(4, 16, 8), 256, 0, stream>>>(Wsh, Wst, Wrw, was, war, Gpart);
  k_g2b<<<64, 256, 0, stream>>>(Gpart, Gb);
  k_const<<<1, 64, 0, stream>>>(bsh, Wst, bst, Wrw, brw, was, bas, war, barr, cv);

  {
    void* args[] = { (void*)&xb, (void*)&whhb, (void*)&wihb, (void*)&bih, (void*)&bhh,
                     (void*)&c0, (void*)&rb, (void*)&outH, (void*)&outC, (void*)&barp };
    hipError_t e = hipLaunchCooperativeKernel((const void*)k_lstm, dim3(256), dim3(256),
                                              args, 0, stream);
    if (e != hipSuccess) {
      // fallback: plain launch (barrier is hand-rolled; 256 blocks at 1/CU co-reside)
      k_lstm<<<256, 256, 0, stream>>>(xb, whhb, wihb, bih, bhh, c0, rb, outH, outC, barp);
    }
  }

  k_proj<<<512, 256, 0, stream>>>(rb, Gb, cv, P);
  k_scan<<<64, 64, 0, stream>>>(P, outS, outR);
}